// Round 2
// baseline (803.156 us; speedup 1.0000x reference)
//
#include <hip/hip_runtime.h>

// Conv1dFFTInt8: B=16, CIN=128, COUT=128, L=4096, out_size==1.
// Identity: ifft(sum_l X[l]W[l])[0] = sum_n x[n] * w[(L-n) mod L]  (real inputs)
// => out[b,o] = bias[o] + sum_i sum_m w[o,i,m] * x[b,i,(L-m)&(L-1)]
// HBM-bound skinny GEMM: weight 256MB read exactly once; x (32MB) L3-resident.

constexpr int LEN   = 4096;
constexpr int CIN_  = 128;
constexpr int COUT_ = 128;
constexpr int BATCH = 16;
constexpr int CHUNK = 512;   // k-chunk staged in LDS (floats per batch row)

__global__ void init_out_kernel(const float* __restrict__ bias, float* __restrict__ out) {
    int t = blockIdx.x * 256 + threadIdx.x;
    if (t < BATCH * COUT_) out[t] = bias[t & (COUT_ - 1)];
}

__device__ __forceinline__ void stage_lds4(const float* g, float* l) {
    __builtin_amdgcn_global_load_lds(
        (const __attribute__((address_space(1))) unsigned int*)g,
        (__attribute__((address_space(3))) unsigned int*)l, 4, 0, 0);
}

// Grid 1024 = ot(8) x ci(128). Block: 256 thr = 4 waves; wave owns 4 cout rows,
// all 16 batches (acc[16][4] in VGPRs). 8 chunks of 512 per block (one channel).
// 3 blocks/CU (32KB LDS, VGPR<=168): barrier stalls of one block overlap with
// the other two blocks' weight streaming.
__global__ __launch_bounds__(256, 3)
void conv_dot_kernel(const float* __restrict__ x, const float* __restrict__ w,
                     float* __restrict__ out) {
    __shared__ float xs[BATCH * CHUNK];   // 32 KB: reversed-x chunk, [b][mm]

    const int tid   = threadIdx.x;
    const int lane  = tid & 63;
    const int wv    = tid >> 6;
    const int bk    = blockIdx.x;        // 0..1023
    const int ot    = bk >> 7;           // 0..7 o-tile
    const int ci    = bk & 127;          // input channel; same-ci blocks -> same XCD
    const int obase = ot * 16 + wv * 4;
    const int phase = (bk >> 3) & 7;     // chunk-order stagger (same-ci share phase)

    const float* xci = x + (ci << 12);

    const float* wrow[4];
#pragma unroll
    for (int j = 0; j < 4; ++j)
        wrow[j] = w + (((obase + j) * CIN_ + ci) << 12);

    float acc[BATCH][4];
#pragma unroll
    for (int b = 0; b < BATCH; ++b)
#pragma unroll
        for (int j = 0; j < 4; ++j) acc[b][j] = 0.f;

    // step t in [0,16): chunk q = ((t>>1)+phase)&7, half s = t&1
    // weight float offset within channel = q*512 + s*256 + lane*4
    float4 wr[4], wn[4];
    {
        const int off0 = (phase << 9) + (lane << 2);
#pragma unroll
        for (int j = 0; j < 4; ++j) wr[j] = *(const float4*)(wrow[j] + off0);
    }

    for (int q8 = 0; q8 < 8; ++q8) {
        const int q  = (q8 + phase) & 7;
        const int m0 = q << 9;
        const int nb = LEN - m0;

        __syncthreads();   // previous chunk's readers done
        // stage xs[b*512 + mm] = x[b, ci, (LEN - m0 - mm) & 4095], direct to LDS
#pragma unroll
        for (int b = 0; b < BATCH; ++b) {
            const float* xb = xci + (b << 19);          // b * CIN*LEN
#pragma unroll
            for (int p = 0; p < 2; ++p) {
                const int n = (nb - (p << 8) - tid) & (LEN - 1);
                stage_lds4(xb + n, xs + (b << 9) + (p << 8) + (wv << 6));
            }
        }
        __syncthreads();   // drains vmcnt -> staged data visible

#pragma unroll
        for (int s = 0; s < 2; ++s) {
            const int t = q8 * 2 + s;
            if (t < 15) {   // prefetch next half-chunk's weights (crosses barriers)
                const int qn   = (((t + 1) >> 1) + phase) & 7;
                const int offn = (qn << 9) + (((t + 1) & 1) << 8) + (lane << 2);
#pragma unroll
                for (int j = 0; j < 4; ++j) wn[j] = *(const float4*)(wrow[j] + offn);
            }
            const float4* xls = (const float4*)xs + (s << 6) + lane;
#pragma unroll
            for (int b = 0; b < BATCH; ++b) {
                const float4 xv = xls[b << 7];   // ds_read_b128, conflict-free
#pragma unroll
                for (int j = 0; j < 4; ++j) {
                    acc[b][j] += xv.x * wr[j].x;
                    acc[b][j] += xv.y * wr[j].y;
                    acc[b][j] += xv.z * wr[j].z;
                    acc[b][j] += xv.w * wr[j].w;
                }
            }
            if (t < 15) {
#pragma unroll
                for (int j = 0; j < 4; ++j) wr[j] = wn[j];
            }
        }
    }

    // epilogue: cross-lane shuffle reduction, one atomic per (b, o) per block
#pragma unroll
    for (int b = 0; b < BATCH; ++b) {
#pragma unroll
        for (int j = 0; j < 4; ++j) {
            float v = acc[b][j];
            v += __shfl_down(v, 32, 64);
            v += __shfl_down(v, 16, 64);
            v += __shfl_down(v, 8, 64);
            v += __shfl_down(v, 4, 64);
            v += __shfl_down(v, 2, 64);
            v += __shfl_down(v, 1, 64);
            if (lane == 0) atomicAdd(out + b * COUT_ + obase + j, v);
        }
    }
}

extern "C" void kernel_launch(void* const* d_in, const int* in_sizes, int n_in,
                              void* d_out, int out_size, void* d_ws, size_t ws_size,
                              hipStream_t stream) {
    const float* x    = (const float*)d_in[0];   // [16,128,4096]
    const float* wgt  = (const float*)d_in[1];   // [128,128,4096]
    const float* bias = (const float*)d_in[2];   // [128]
    float* out = (float*)d_out;                  // [16,128,1]
    (void)in_sizes; (void)n_in; (void)d_ws; (void)ws_size; (void)out_size;

    init_out_kernel<<<8, 256, 0, stream>>>(bias, out);
    conv_dot_kernel<<<1024, 256, 0, stream>>>(x, wgt, out);
}